// Round 12
// baseline (695.994 us; speedup 1.0000x reference)
//
#include <hip/hip_runtime.h>
#include <hip/hip_bf16.h>

#define SEQ  8192
#define DIN  768
#define DOUT 64

typedef __attribute__((ext_vector_type(8))) short short8;
typedef __attribute__((ext_vector_type(4))) short s16x4;
typedef __attribute__((ext_vector_type(4))) float f32x4;

__device__ inline unsigned short f2bf(float f) {
    __hip_bfloat16 h = __float2bfloat16(f);
    return __builtin_bit_cast(unsigned short, h);
}

// ---------------------------------------------------------------------------
// Kernel 1: fold Wq/Wk/Wv (fp32 [768][64]) into Wf bf16, FRAGMENT-ORDERED for
// proj's direct MFMA B-operand loads:
//   Wf[((kt*12+nt)*2+h)*512 + g*128 + l15*8 + e] = W[ch=nt*16+l15][k=kt*64+h*32+g*8+e]
// Wq block gets (1/sqrt(64))*log2(e) folded in -> softmax runs in exp2 domain.
// ---------------------------------------------------------------------------
__global__ __launch_bounds__(256) void wconv_kernel(
    const float* __restrict__ Wq, const float* __restrict__ Wk,
    const float* __restrict__ Wv, unsigned short* __restrict__ Wf) {
    int idx = blockIdx.x * 256 + threadIdx.x;   // 0 .. 192*768-1
    int c = idx / DIN;                          // 0..191 output channel
    int k = idx - c * DIN;                      // 0..767
    int sel = c >> 6, cc = c & 63;
    const float* W = (sel == 0) ? Wq : ((sel == 1) ? Wk : Wv);
    float v = W[k * DOUT + cc];
    if (sel == 0) v *= 0.125f * 1.4426950408889634f;   // (1/sqrt(d_k)) * log2(e)
    int nt = c >> 4, l15 = c & 15;
    int kt = k >> 6, k6 = k & 63;
    int h  = k6 >> 5, r5 = k6 & 31, g = r5 >> 3, e = r5 & 7;
    Wf[(((kt * 12 + nt) * 2 + h) << 9) + (g << 7) + (l15 << 3) + e] = f2bf(v);
}

// ---------------------------------------------------------------------------
// Kernel 2: projection GEMM. 512 blocks x 256 threads (4 waves), 16 rows/block;
// wave w computes output channels [w*48, w*48+48) (3 nt tiles).
// W fragments loaded DIRECT from fragment-ordered Wf (L2-resident, coalesced
// short8) -- no W LDS (zero cross-wave reuse), only a double-buffered x tile
// (1 barrier/kt). Outputs PRE-SWIZZLED for flash (32-kv subtiles):
//   Q8 [8192][64] bf16 row-major
//   Kf [(sc*2+nt)*2+h][lane(g*16+l15)][8] : K[kv=sc*32+nt*16+l15][d=h*32+g*8+e]
//   Vf [sc*4+dn][lane(g*16+l15)][8]       : V[kv=sc*32+(j>>2)*16+4g+(j&3)][d=dn*16+l15]
// ---------------------------------------------------------------------------
__global__ __launch_bounds__(256) void proj_kernel(
    const float* __restrict__ x, const unsigned short* __restrict__ Wf,
    unsigned short* __restrict__ Q8, unsigned short* __restrict__ Kf,
    unsigned short* __restrict__ Vf) {
    __shared__ unsigned short xs[2][16 * 72];  // x tile dbuf [16 rows][64 k] pitch 72

    const int tid  = threadIdx.x;
    const int m0   = blockIdx.x * 16;
    const int lane = tid & 63;
    const int w    = tid >> 6;          // wave 0..3
    const int g    = lane >> 4;
    const int l15  = lane & 15;
    const int sr   = tid >> 4;          // stage row 0..15
    const int sc4  = (tid & 15) * 4;    // stage col

    f32x4 zero = {0.f, 0.f, 0.f, 0.f};
    f32x4 acc[3] = {zero, zero, zero};

    // prologue: stage kt=0
    {
        float4 f = *reinterpret_cast<const float4*>(&x[(m0 + sr) * DIN + sc4]);
        s16x4 o4;
        o4[0] = (short)f2bf(f.x); o4[1] = (short)f2bf(f.y);
        o4[2] = (short)f2bf(f.z); o4[3] = (short)f2bf(f.w);
        *(s16x4*)&xs[0][sr * 72 + sc4] = o4;
    }
    __syncthreads();

    for (int kt = 0; kt < 12; ++kt) {
        const int cur = kt & 1;
        // ---- A fragments from LDS ----
        short8 a0 = *(short8*)&xs[cur][l15 * 72 + g * 8];
        short8 a1 = *(short8*)&xs[cur][l15 * 72 + g * 8 + 32];
        // ---- stage kt+1 into other buffer ----
        if (kt + 1 < 12) {
            float4 f = *reinterpret_cast<const float4*>(
                &x[(m0 + sr) * DIN + (kt + 1) * 64 + sc4]);
            s16x4 o4;
            o4[0] = (short)f2bf(f.x); o4[1] = (short)f2bf(f.y);
            o4[2] = (short)f2bf(f.z); o4[3] = (short)f2bf(f.w);
            *(s16x4*)&xs[cur ^ 1][sr * 72 + sc4] = o4;
        }
        // ---- W fragments direct from global (coalesced, L2-resident) ----
#pragma unroll
        for (int i = 0; i < 3; ++i) {
            int nt = w * 3 + i;
            const unsigned short* wb = &Wf[((kt * 12 + nt) * 2) * 512 + lane * 8];
            short8 b0 = *(const short8*)wb;
            short8 b1 = *(const short8*)(wb + 512);
            acc[i] = __builtin_amdgcn_mfma_f32_16x16x32_bf16(a0, b0, acc[i], 0, 0, 0);
            acc[i] = __builtin_amdgcn_mfma_f32_16x16x32_bf16(a1, b1, acc[i], 0, 0, 0);
        }
        __syncthreads();
    }
#pragma unroll
    for (int i = 0; i < 3; ++i) {
#pragma unroll
        for (int r = 0; r < 4; ++r) {
            int row = m0 + g * 4 + r;                 // SEQ index
            int col = (w * 3 + i) * 16 + l15;
            unsigned short b = f2bf(acc[i][r]);
            if (col < 64) {
                Q8[row * 64 + col] = b;
            } else if (col < 128) {
                int d  = col - 64;
                int t  = row >> 6, nt = (row >> 4) & 3, lk = row & 15;
                int h  = d >> 5, kg = (d >> 3) & 3, e = d & 7;
                Kf[(((t * 4 + nt) * 2 + h) * 64 + kg * 16 + lk) * 8 + e] = b;
            } else {
                int d  = col - 128;
                int kv = row;
                int t  = kv >> 6, k6 = kv & 63;
                int c  = k6 >> 5, r5 = k6 & 31;
                int hf = r5 >> 4, vg = (r5 >> 2) & 3, j = (r5 & 3) + hf * 4;
                int dn = d >> 4, lv = d & 15;
                Vf[(((t * 2 + c) * 4 + dn) * 64 + vg * 16 + lv) * 8 + j] = b;
            }
        }
    }
}

// ---------------------------------------------------------------------------
// Kernel 3: flash attention, swapped-operand, zero LDS, zero barriers,
// fixed softmax base (m=0, exp2 domain). qrows=64/wave (4 qg groups).
// Grid (32, NS=16) x 256 threads, __launch_bounds__(256,2): ~226 live VGPR.
// K AND V both double-buffered with full-subtile prefetch distance:
// QK(i) -> prefetch K(i+1),V(i+1) -> softmax(i) -> PV(i). Branch-free body.
// ---------------------------------------------------------------------------
__global__ __launch_bounds__(256, 2) void flash_kernel(
    const unsigned short* __restrict__ Q8, const unsigned short* __restrict__ Kf,
    const unsigned short* __restrict__ Vf, float* __restrict__ Op,
    float* __restrict__ Lp, int ntiles) {
    const int tid  = threadIdx.x;
    const int w    = tid >> 6;
    const int lane = tid & 63;
    const int g    = lane >> 4;
    const int l15  = lane & 15;
    const int q0   = (blockIdx.x * 4 + w) * 64;
    const int nsub = ntiles * 2;
    const int sub0 = blockIdx.y * nsub;            // first 32-kv subtile

    // Q fragments: qa[qg*2+h] = Q8[q0+qg*16+l15][g*8 + 32h .. +7]
    short8 qa[8];
#pragma unroll
    for (int qg = 0; qg < 4; ++qg) {
        qa[qg * 2 + 0] = *(const short8*)&Q8[(q0 + qg * 16 + l15) * 64 + g * 8];
        qa[qg * 2 + 1] = *(const short8*)&Q8[(q0 + qg * 16 + l15) * 64 + g * 8 + 32];
    }

    f32x4 zero = {0.f, 0.f, 0.f, 0.f};
    f32x4 o[4][4];
    float ln[4] = {0.f, 0.f, 0.f, 0.f};            // per-lane PARTIAL sums
#pragma unroll
    for (int qg = 0; qg < 4; ++qg)
#pragma unroll
        for (int dn = 0; dn < 4; ++dn) o[qg][dn] = zero;

    const unsigned short* kfp = Kf + (size_t)sub0 * 2048 + lane * 8;
    const unsigned short* vfp = Vf + (size_t)sub0 * 2048 + lane * 8;

    // prologue: K(0), V(0)
    short8 kb[2][2], vbuf[2][4];
#pragma unroll
    for (int nt = 0; nt < 2; ++nt)
#pragma unroll
        for (int h = 0; h < 2; ++h)
            kb[nt][h] = *(const short8*)&kfp[(nt * 2 + h) * 512];
#pragma unroll
    for (int dn = 0; dn < 4; ++dn)
        vbuf[0][dn] = *(const short8*)&vfp[dn * 512];

    for (int i = 0; i < nsub; ++i) {
        const int cur = i & 1;
        // ---- S^T = K @ Q (16 MFMAs) ----
        f32x4 s[4][2];
#pragma unroll
        for (int qg = 0; qg < 4; ++qg)
#pragma unroll
            for (int nt = 0; nt < 2; ++nt) s[qg][nt] = zero;
#pragma unroll
        for (int nt = 0; nt < 2; ++nt)
#pragma unroll
            for (int qg = 0; qg < 4; ++qg) {
                s[qg][nt] = __builtin_amdgcn_mfma_f32_16x16x32_bf16(kb[nt][0], qa[qg * 2 + 0], s[qg][nt], 0, 0, 0);
                s[qg][nt] = __builtin_amdgcn_mfma_f32_16x16x32_bf16(kb[nt][1], qa[qg * 2 + 1], s[qg][nt], 0, 0, 0);
            }

        // ---- prefetch K(i+1), V(i+1) (full-subtile issue distance) ----
        if (i + 1 < nsub) {
#pragma unroll
            for (int nt = 0; nt < 2; ++nt)
#pragma unroll
                for (int h = 0; h < 2; ++h)
                    kb[nt][h] = *(const short8*)&kfp[(size_t)(i + 1) * 2048 + (nt * 2 + h) * 512];
#pragma unroll
            for (int dn = 0; dn < 4; ++dn)
                vbuf[cur ^ 1][dn] = *(const short8*)&vfp[(size_t)(i + 1) * 2048 + dn * 512];
        }

        // ---- softmax numerator, fixed base m=0 (exp2 domain), branch-free ----
        short8 pa[4];
#pragma unroll
        for (int qg = 0; qg < 4; ++qg) {
            float p[8];
#pragma unroll
            for (int nt = 0; nt < 2; ++nt)
#pragma unroll
                for (int r = 0; r < 4; ++r)
                    p[nt * 4 + r] = __builtin_amdgcn_exp2f(s[qg][nt][r]);
            ln[qg] += ((p[0] + p[1]) + (p[2] + p[3])) + ((p[4] + p[5]) + (p[6] + p[7]));
            short8 pk;
#pragma unroll
            for (int j = 0; j < 8; ++j) pk[j] = (short)f2bf(p[j]);
            pa[qg] = pk;
        }

        // ---- O^T += V^T @ P (16 MFMAs) ----
#pragma unroll
        for (int dn = 0; dn < 4; ++dn)
#pragma unroll
            for (int qg = 0; qg < 4; ++qg)
                o[qg][dn] = __builtin_amdgcn_mfma_f32_16x16x32_bf16(vbuf[cur][dn], pa[qg], o[qg][dn], 0, 0, 0);
    }

    // ---- epilogue: reduce ln across the row (only cross-lane op), store ----
    const size_t sb = (size_t)blockIdx.y * SEQ;
#pragma unroll
    for (int qg = 0; qg < 4; ++qg) {
        float ps = ln[qg];
        ps += __shfl_xor(ps, 16);
        ps += __shfl_xor(ps, 32);
#pragma unroll
        for (int dn = 0; dn < 4; ++dn)
            *(f32x4*)&Op[(sb + q0 + qg * 16 + l15) * 64 + dn * 16 + 4 * g] = o[qg][dn];
        if (g == 0) {
            Lp[sb + q0 + qg * 16 + l15] = ps;
        }
    }
}

// ---------------------------------------------------------------------------
// Kernel 4: combine split partials: plain sums (fixed softmax base).
// 512 blocks x 256 threads; 16 q-rows/block, f32x4 per thread.
// ---------------------------------------------------------------------------
__global__ __launch_bounds__(256) void reduce_kernel(
    const float* __restrict__ Op, const float* __restrict__ Lp,
    float* __restrict__ Out, int NS) {
    int q  = blockIdx.x * 16 + (threadIdx.x >> 4);
    int d4 = (threadIdx.x & 15) * 4;
    float L = 0.f;
    f32x4 acc = {0.f, 0.f, 0.f, 0.f};
    for (int s = 0; s < NS; ++s) {
        L   += Lp[s * SEQ + q];
        acc += *(const f32x4*)&Op[((size_t)s * SEQ + q) * 64 + d4];
    }
    float inv = 1.0f / L;
    f32x4 r = {acc[0] * inv, acc[1] * inv, acc[2] * inv, acc[3] * inv};
    *(f32x4*)&Out[q * 64 + d4] = r;
}

// ---------------------------------------------------------------------------
extern "C" void kernel_launch(void* const* d_in, const int* in_sizes, int n_in,
                              void* d_out, int out_size, void* d_ws, size_t ws_size,
                              hipStream_t stream) {
    const float* x  = (const float*)d_in[0];
    const float* Wq = (const float*)d_in[1];
    const float* Wk = (const float*)d_in[2];
    const float* Wv = (const float*)d_in[3];
    float* out = (float*)d_out;

    char* ws = (char*)d_ws;
    unsigned short* Wf = (unsigned short*)(ws);                       // 294912 B
    unsigned short* Q8 = (unsigned short*)(ws + 294912);              // 1 MiB
    unsigned short* Kf = (unsigned short*)(ws + 294912 + 1048576);    // 1 MiB
    unsigned short* Vf = (unsigned short*)(ws + 294912 + 2097152);    // 1 MiB
    const size_t fixed = 294912 + 3 * 1048576;                        // 3440640

    // split count: 16 (qrows=64/wave -> 512 blocks = 2/CU exactly)
    int NS = 16;
    while (NS > 1 && fixed + (size_t)NS * (2097152 + 32768) > ws_size) NS >>= 1;
    float* Op = (float*)(ws + fixed);                                  // NS*2 MiB
    float* Lp = (float*)(ws + fixed + (size_t)NS * 2097152);           // NS*32 KiB
    const int ntiles = SEQ / (NS * 64);

    wconv_kernel<<<dim3(576), dim3(256), 0, stream>>>(Wq, Wk, Wv, Wf);
    proj_kernel<<<dim3(512), dim3(256), 0, stream>>>(x, Wf, Q8, Kf, Vf);
    flash_kernel<<<dim3(32, NS), dim3(256), 0, stream>>>(Q8, Kf, Vf, Op, Lp, ntiles);
    reduce_kernel<<<dim3(512), dim3(256), 0, stream>>>(Op, Lp, out, NS);
}

// Round 13
// 49.244 us; speedup vs baseline: 14.1336x; 14.1336x over previous
//
#include <hip/hip_runtime.h>
#include <hip/hip_bf16.h>

#define SEQ  8192
#define DIN  768
#define DOUT 64

typedef __attribute__((ext_vector_type(8))) short short8;
typedef __attribute__((ext_vector_type(4))) short s16x4;
typedef __attribute__((ext_vector_type(4))) float f32x4;

__device__ inline unsigned short f2bf(float f) {
    __hip_bfloat16 h = __float2bfloat16(f);
    return __builtin_bit_cast(unsigned short, h);
}

// ---------------------------------------------------------------------------
// Kernel 1: fold Wq/Wk/Wv (fp32 [768][64]) into Wf bf16, FRAGMENT-ORDERED for
// proj's direct MFMA B-operand loads:
//   Wf[((kt*12+nt)*2+h)*512 + g*128 + l15*8 + e] = W[ch=nt*16+l15][k=kt*64+h*32+g*8+e]
// Wq block gets (1/sqrt(64))*log2(e) folded in -> softmax runs in exp2 domain.
// ---------------------------------------------------------------------------
__global__ __launch_bounds__(256) void wconv_kernel(
    const float* __restrict__ Wq, const float* __restrict__ Wk,
    const float* __restrict__ Wv, unsigned short* __restrict__ Wf) {
    int idx = blockIdx.x * 256 + threadIdx.x;   // 0 .. 192*768-1
    int c = idx / DIN;                          // 0..191 output channel
    int k = idx - c * DIN;                      // 0..767
    int sel = c >> 6, cc = c & 63;
    const float* W = (sel == 0) ? Wq : ((sel == 1) ? Wk : Wv);
    float v = W[k * DOUT + cc];
    if (sel == 0) v *= 0.125f * 1.4426950408889634f;   // (1/sqrt(d_k)) * log2(e)
    int nt = c >> 4, l15 = c & 15;
    int kt = k >> 6, k6 = k & 63;
    int h  = k6 >> 5, r5 = k6 & 31, g = r5 >> 3, e = r5 & 7;
    Wf[(((kt * 12 + nt) * 2 + h) << 9) + (g << 7) + (l15 << 3) + e] = f2bf(v);
}

// ---------------------------------------------------------------------------
// Kernel 2: projection GEMM. 512 blocks x 256 threads (4 waves), 16 rows/block;
// wave w computes output channels [w*48, w*48+48) (3 nt tiles).
// W fragments loaded DIRECT from fragment-ordered Wf (L2-resident, coalesced
// short8) -- no W LDS (zero cross-wave reuse); double-buffered x tile,
// 1 barrier/kt. Outputs PRE-SWIZZLED for flash (32-kv subtiles):
//   Q8 [8192][64] bf16 row-major
//   Kf [(sc*2+nt)*2+h][lane(g*16+l15)][8] : K[kv=sc*32+nt*16+l15][d=h*32+g*8+e]
//   Vf [sc*4+dn][lane(g*16+l15)][8]       : V[kv=sc*32+(j>>2)*16+4g+(j&3)][d=dn*16+l15]
// ---------------------------------------------------------------------------
__global__ __launch_bounds__(256) void proj_kernel(
    const float* __restrict__ x, const unsigned short* __restrict__ Wf,
    unsigned short* __restrict__ Q8, unsigned short* __restrict__ Kf,
    unsigned short* __restrict__ Vf) {
    __shared__ unsigned short xs[2][16 * 72];  // x tile dbuf [16 rows][64 k] pitch 72

    const int tid  = threadIdx.x;
    const int m0   = blockIdx.x * 16;
    const int lane = tid & 63;
    const int w    = tid >> 6;          // wave 0..3
    const int g    = lane >> 4;
    const int l15  = lane & 15;
    const int sr   = tid >> 4;          // stage row 0..15
    const int sc4  = (tid & 15) * 4;    // stage col

    f32x4 zero = {0.f, 0.f, 0.f, 0.f};
    f32x4 acc[3] = {zero, zero, zero};

    // prologue: stage kt=0
    {
        float4 f = *reinterpret_cast<const float4*>(&x[(m0 + sr) * DIN + sc4]);
        s16x4 o4;
        o4[0] = (short)f2bf(f.x); o4[1] = (short)f2bf(f.y);
        o4[2] = (short)f2bf(f.z); o4[3] = (short)f2bf(f.w);
        *(s16x4*)&xs[0][sr * 72 + sc4] = o4;
    }
    __syncthreads();

    for (int kt = 0; kt < 12; ++kt) {
        const int cur = kt & 1;
        // ---- A fragments from LDS ----
        short8 a0 = *(short8*)&xs[cur][l15 * 72 + g * 8];
        short8 a1 = *(short8*)&xs[cur][l15 * 72 + g * 8 + 32];
        // ---- stage kt+1 into other buffer ----
        if (kt + 1 < 12) {
            float4 f = *reinterpret_cast<const float4*>(
                &x[(m0 + sr) * DIN + (kt + 1) * 64 + sc4]);
            s16x4 o4;
            o4[0] = (short)f2bf(f.x); o4[1] = (short)f2bf(f.y);
            o4[2] = (short)f2bf(f.z); o4[3] = (short)f2bf(f.w);
            *(s16x4*)&xs[cur ^ 1][sr * 72 + sc4] = o4;
        }
        // ---- W fragments direct from global (coalesced, L2-resident) ----
#pragma unroll
        for (int i = 0; i < 3; ++i) {
            int nt = w * 3 + i;
            const unsigned short* wb = &Wf[((kt * 12 + nt) * 2) * 512 + lane * 8];
            short8 b0 = *(const short8*)wb;
            short8 b1 = *(const short8*)(wb + 512);
            acc[i] = __builtin_amdgcn_mfma_f32_16x16x32_bf16(a0, b0, acc[i], 0, 0, 0);
            acc[i] = __builtin_amdgcn_mfma_f32_16x16x32_bf16(a1, b1, acc[i], 0, 0, 0);
        }
        __syncthreads();
    }
#pragma unroll
    for (int i = 0; i < 3; ++i) {
#pragma unroll
        for (int r = 0; r < 4; ++r) {
            int row = m0 + g * 4 + r;                 // SEQ index
            int col = (w * 3 + i) * 16 + l15;
            unsigned short b = f2bf(acc[i][r]);
            if (col < 64) {
                Q8[row * 64 + col] = b;
            } else if (col < 128) {
                int d  = col - 64;
                int t  = row >> 6, nt = (row >> 4) & 3, lk = row & 15;
                int h  = d >> 5, kg = (d >> 3) & 3, e = d & 7;
                Kf[(((t * 4 + nt) * 2 + h) * 64 + kg * 16 + lk) * 8 + e] = b;
            } else {
                int d  = col - 128;
                int kv = row;
                int t  = kv >> 6, k6 = kv & 63;
                int c  = k6 >> 5, r5 = k6 & 31;
                int hf = r5 >> 4, vg = (r5 >> 2) & 3, j = (r5 & 3) + hf * 4;
                int dn = d >> 4, lv = d & 15;
                Vf[(((t * 2 + c) * 4 + dn) * 64 + vg * 16 + lv) * 8 + j] = b;
            }
        }
    }
}

// ---------------------------------------------------------------------------
// Kernel 3: flash attention, swapped-operand, zero LDS, zero barriers,
// fixed softmax base (m=0, exp2 domain). qrows=64/wave (4 qg groups).
// Grid (32, NS=16) x 256 threads, __launch_bounds__(256,2).
// V double-buffered via MANUAL 2x loop unroll with NAMED buffers vA/vB
// (all register-array indices compile-time constant -- rule-#20 fix for the
// round-12 scratch disaster). QK(i) -> prefetch K(i+1),V(i+1) -> softmax ->
// PV(i). Branch-free body. nsub is even (16) so no tail step.
// ---------------------------------------------------------------------------
__global__ __launch_bounds__(256, 2) void flash_kernel(
    const unsigned short* __restrict__ Q8, const unsigned short* __restrict__ Kf,
    const unsigned short* __restrict__ Vf, float* __restrict__ Op,
    float* __restrict__ Lp, int ntiles) {
    const int tid  = threadIdx.x;
    const int w    = tid >> 6;
    const int lane = tid & 63;
    const int g    = lane >> 4;
    const int l15  = lane & 15;
    const int q0   = (blockIdx.x * 4 + w) * 64;
    const int nsub = ntiles * 2;
    const int sub0 = blockIdx.y * nsub;            // first 32-kv subtile

    // Q fragments: qa[qg*2+h] = Q8[q0+qg*16+l15][g*8 + 32h .. +7]
    short8 qa[8];
#pragma unroll
    for (int qg = 0; qg < 4; ++qg) {
        qa[qg * 2 + 0] = *(const short8*)&Q8[(q0 + qg * 16 + l15) * 64 + g * 8];
        qa[qg * 2 + 1] = *(const short8*)&Q8[(q0 + qg * 16 + l15) * 64 + g * 8 + 32];
    }

    f32x4 zero = {0.f, 0.f, 0.f, 0.f};
    f32x4 o[4][4];
    float ln[4] = {0.f, 0.f, 0.f, 0.f};            // per-lane PARTIAL sums
#pragma unroll
    for (int qg = 0; qg < 4; ++qg)
#pragma unroll
        for (int dn = 0; dn < 4; ++dn) o[qg][dn] = zero;

    const unsigned short* kfp = Kf + (size_t)sub0 * 2048 + lane * 8;
    const unsigned short* vfp = Vf + (size_t)sub0 * 2048 + lane * 8;

    // prologue: K(0) -> kb, V(0) -> vA
    short8 kb[2][2], vA[4], vB[4];
#pragma unroll
    for (int nt = 0; nt < 2; ++nt)
#pragma unroll
        for (int h = 0; h < 2; ++h)
            kb[nt][h] = *(const short8*)&kfp[(nt * 2 + h) * 512];
#pragma unroll
    for (int dn = 0; dn < 4; ++dn)
        vA[dn] = *(const short8*)&vfp[dn * 512];

    // One subtile step; VCUR/VNXT are *named* arrays -> constant indices only.
#define FLASH_STEP(I, VCUR, VNXT)                                                            \
    {                                                                                        \
        f32x4 s[4][2];                                                                       \
        _Pragma("unroll")                                                                    \
        for (int qg = 0; qg < 4; ++qg)                                                       \
            _Pragma("unroll")                                                                \
            for (int nt = 0; nt < 2; ++nt) s[qg][nt] = zero;                                 \
        _Pragma("unroll")                                                                    \
        for (int nt = 0; nt < 2; ++nt)                                                       \
            _Pragma("unroll")                                                                \
            for (int qg = 0; qg < 4; ++qg) {                                                 \
                s[qg][nt] = __builtin_amdgcn_mfma_f32_16x16x32_bf16(kb[nt][0], qa[qg * 2 + 0], s[qg][nt], 0, 0, 0); \
                s[qg][nt] = __builtin_amdgcn_mfma_f32_16x16x32_bf16(kb[nt][1], qa[qg * 2 + 1], s[qg][nt], 0, 0, 0); \
            }                                                                                \
        if ((I) + 1 < nsub) {                                                                \
            _Pragma("unroll")                                                                \
            for (int nt = 0; nt < 2; ++nt)                                                   \
                _Pragma("unroll")                                                            \
                for (int h = 0; h < 2; ++h)                                                  \
                    kb[nt][h] = *(const short8*)&kfp[(size_t)((I) + 1) * 2048 + (nt * 2 + h) * 512]; \
            _Pragma("unroll")                                                                \
            for (int dn = 0; dn < 4; ++dn)                                                   \
                VNXT[dn] = *(const short8*)&vfp[(size_t)((I) + 1) * 2048 + dn * 512];        \
        }                                                                                    \
        short8 pa[4];                                                                        \
        _Pragma("unroll")                                                                    \
        for (int qg = 0; qg < 4; ++qg) {                                                     \
            float p[8];                                                                      \
            _Pragma("unroll")                                                                \
            for (int nt = 0; nt < 2; ++nt)                                                   \
                _Pragma("unroll")                                                            \
                for (int r = 0; r < 4; ++r)                                                  \
                    p[nt * 4 + r] = __builtin_amdgcn_exp2f(s[qg][nt][r]);                    \
            ln[qg] += ((p[0] + p[1]) + (p[2] + p[3])) + ((p[4] + p[5]) + (p[6] + p[7]));     \
            short8 pk;                                                                       \
            _Pragma("unroll")                                                                \
            for (int j = 0; j < 8; ++j) pk[j] = (short)f2bf(p[j]);                           \
            pa[qg] = pk;                                                                     \
        }                                                                                    \
        _Pragma("unroll")                                                                    \
        for (int dn = 0; dn < 4; ++dn)                                                       \
            _Pragma("unroll")                                                                \
            for (int qg = 0; qg < 4; ++qg)                                                   \
                o[qg][dn] = __builtin_amdgcn_mfma_f32_16x16x32_bf16(VCUR[dn], pa[qg], o[qg][dn], 0, 0, 0); \
    }

    for (int i = 0; i < nsub; i += 2) {
        FLASH_STEP(i, vA, vB)
        FLASH_STEP(i + 1, vB, vA)
    }
#undef FLASH_STEP

    // ---- epilogue: reduce ln across the row (only cross-lane op), store ----
    const size_t sb = (size_t)blockIdx.y * SEQ;
#pragma unroll
    for (int qg = 0; qg < 4; ++qg) {
        float ps = ln[qg];
        ps += __shfl_xor(ps, 16);
        ps += __shfl_xor(ps, 32);
#pragma unroll
        for (int dn = 0; dn < 4; ++dn)
            *(f32x4*)&Op[(sb + q0 + qg * 16 + l15) * 64 + dn * 16 + 4 * g] = o[qg][dn];
        if (g == 0) {
            Lp[sb + q0 + qg * 16 + l15] = ps;
        }
    }
}

// ---------------------------------------------------------------------------
// Kernel 4: combine split partials: plain sums (fixed softmax base).
// 512 blocks x 256 threads; 16 q-rows/block, f32x4 per thread.
// ---------------------------------------------------------------------------
__global__ __launch_bounds__(256) void reduce_kernel(
    const float* __restrict__ Op, const float* __restrict__ Lp,
    float* __restrict__ Out, int NS) {
    int q  = blockIdx.x * 16 + (threadIdx.x >> 4);
    int d4 = (threadIdx.x & 15) * 4;
    float L = 0.f;
    f32x4 acc = {0.f, 0.f, 0.f, 0.f};
    for (int s = 0; s < NS; ++s) {
        L   += Lp[s * SEQ + q];
        acc += *(const f32x4*)&Op[((size_t)s * SEQ + q) * 64 + d4];
    }
    float inv = 1.0f / L;
    f32x4 r = {acc[0] * inv, acc[1] * inv, acc[2] * inv, acc[3] * inv};
    *(f32x4*)&Out[q * 64 + d4] = r;
}

// ---------------------------------------------------------------------------
extern "C" void kernel_launch(void* const* d_in, const int* in_sizes, int n_in,
                              void* d_out, int out_size, void* d_ws, size_t ws_size,
                              hipStream_t stream) {
    const float* x  = (const float*)d_in[0];
    const float* Wq = (const float*)d_in[1];
    const float* Wk = (const float*)d_in[2];
    const float* Wv = (const float*)d_in[3];
    float* out = (float*)d_out;

    char* ws = (char*)d_ws;
    unsigned short* Wf = (unsigned short*)(ws);                       // 294912 B
    unsigned short* Q8 = (unsigned short*)(ws + 294912);              // 1 MiB
    unsigned short* Kf = (unsigned short*)(ws + 294912 + 1048576);    // 1 MiB
    unsigned short* Vf = (unsigned short*)(ws + 294912 + 2097152);    // 1 MiB
    const size_t fixed = 294912 + 3 * 1048576;                        // 3440640

    // split count: 16 (qrows=64/wave -> 512 blocks = 2/CU exactly)
    int NS = 16;
    while (NS > 1 && fixed + (size_t)NS * (2097152 + 32768) > ws_size) NS >>= 1;
    float* Op = (float*)(ws + fixed);                                  // NS*2 MiB
    float* Lp = (float*)(ws + fixed + (size_t)NS * 2097152);           // NS*32 KiB
    const int ntiles = SEQ / (NS * 64);

    wconv_kernel<<<dim3(576), dim3(256), 0, stream>>>(Wq, Wk, Wv, Wf);
    proj_kernel<<<dim3(512), dim3(256), 0, stream>>>(x, Wf, Q8, Kf, Vf);
    flash_kernel<<<dim3(32, NS), dim3(256), 0, stream>>>(Q8, Kf, Vf, Op, Lp, ntiles);
    reduce_kernel<<<dim3(512), dim3(256), 0, stream>>>(Op, Lp, out, NS);
}